// Round 7
// baseline (130.905 us; speedup 1.0000x reference)
//
#include <hip/hip_runtime.h>
#include <math.h>

// Problem constants: gts/preds [4, 8192, 3] fp32; out [4] fp32.
#define BB 4
#define NPTS 8192
#define THREADS 512                    // 8 waves/block
#define NQ_TOTAL (2 * BB * NPTS)       // 65536 (dir,b,point) slots
#define QBLK 512                       // queries per block (8 waves x 64)
#define QPWV 64                        // queries per wave (2 B-frags)
#define QUARTN 2048                    // refs per block (4-way ref split)
#define CHUNK 2048                     // single LDS chunk (32 KB)
#define NFRAG (CHUNK / 32)             // 64 A-frags
#define GLDS_PER_WAVE (CHUNK / 8 / 64) // 4 global_load_lds per wave
#define FBLK 512                       // 4 quarters x 2 dir x 4 b x 16 qgroups
#define REPEAT 6                       // DIAGNOSTIC: re-walk refs 6x so the
                                       // kernel rises above the 40us harness
                                       // fill and produces a counter row.
                                       // atomicMin is idempotent -> results
                                       // bit-identical; per-pass = dur/6.

typedef __attribute__((ext_vector_type(8)))  short bf16x8;   // MFMA A/B frag
typedef __attribute__((ext_vector_type(16))) float f32x16;   // MFMA C/D frag

// ws layout:
//   refpack: NQ_TOTAL uint4  bf16 [x,y,z,rr_hi,rr_lo,1,1,0]       1 MiB
//   qpack:   NQ_TOTAL uint4  bf16 [-2x,-2y,-2z,1,1,qq_hi,qq_lo,0] 1 MiB
//   minpart: NQ_TOTAL uint (fp32-as-uint partial d^2 mins)        256 KiB
// MFMA dot = -2 q.r + rr + qq = |q-r|^2 on bf16-rounded points.
//
// R22 = R21 + (a) deferred fold (the fold consumes the D-pair issued one
// STEP earlier, ~70cy old -> no per-wave MFMA-latency stall; this is the
// one combination not yet tested: R20 had deferred fold at 2 waves/SIMD,
// R21 had immediate fold at 4 waves/SIMD) + (b) REPEAT=6 diagnostic.

__device__ __forceinline__ unsigned short f2bf(float f) {   // RNE f32->bf16
    unsigned u = __float_as_uint(f);
    u += 0x7FFF + ((u >> 16) & 1);
    return (unsigned short)(u >> 16);
}
__device__ __forceinline__ float bf2f(unsigned short h) {
    return __uint_as_float(((unsigned)h) << 16);
}

// ---------------------------------------------------------------------------
// Kernel 1: round coords to bf16, build ref- and query-side fragments.
// Also zero-inits out[0..3] and re-inits minpart to FLT_MAX (ws is poisoned
// by the harness every iteration).
// ---------------------------------------------------------------------------
__global__ __launch_bounds__(256) void pack_kernel(
    const float* __restrict__ gts, const float* __restrict__ preds,
    uint4* __restrict__ refpack, uint4* __restrict__ qpack,
    unsigned* __restrict__ minpart, float* __restrict__ out) {
    int idx = blockIdx.x * 256 + threadIdx.x;
    if (idx < BB) out[idx] = 0.0f;
    if (idx >= NQ_TOTAL) return;
    minpart[idx] = 0x7F7FFFFFu;            // FLT_MAX bits
    int set  = idx / (BB * NPTS);          // 0 = gts, 1 = preds
    int pidx = idx - set * (BB * NPTS);
    const float* src = set ? preds : gts;
    unsigned short hx = f2bf(src[pidx * 3 + 0]);
    unsigned short hy = f2bf(src[pidx * 3 + 1]);
    unsigned short hz = f2bf(src[pidx * 3 + 2]);
    float fx = bf2f(hx), fy = bf2f(hy), fz = bf2f(hz);
    float rr = fmaf(fx, fx, fmaf(fy, fy, fz * fz));
    unsigned short hrr = f2bf(rr);
    unsigned short hlo = f2bf(rr - bf2f(hrr));
    const unsigned short ONE = 0x3F80;      // 1.0 bf16

    uint4 rv;                               // ref slots: [x,y,z,rrhi,rrlo,1,1,0]
    rv.x = (unsigned)hx  | ((unsigned)hy  << 16);
    rv.y = (unsigned)hz  | ((unsigned)hrr << 16);
    rv.z = (unsigned)hlo | ((unsigned)ONE << 16);
    rv.w = (unsigned)ONE;
    refpack[idx] = rv;

    unsigned short nx = f2bf(-2.0f * fx);   // exact (coords already bf16)
    unsigned short ny = f2bf(-2.0f * fy);
    unsigned short nz = f2bf(-2.0f * fz);
    uint4 qv;                               // query slots: [-2x,-2y,-2z,1,1,qqhi,qqlo,0]
    qv.x = (unsigned)nx  | ((unsigned)ny  << 16);
    qv.y = (unsigned)nz  | ((unsigned)ONE << 16);
    qv.z = (unsigned)ONE | ((unsigned)hrr << 16);
    qv.w = (unsigned)hlo;
    qpack[idx] = qv;
}

// Fold one D frag into 4 independent running-min chains (v_min3 pairs).
#define FOLD8(P, X0, X1, X2, X3)                                   \
    X0 = fminf(fminf((P)[0],  (P)[1]),  X0);                       \
    X1 = fminf(fminf((P)[2],  (P)[3]),  X1);                       \
    X2 = fminf(fminf((P)[4],  (P)[5]),  X2);                       \
    X3 = fminf(fminf((P)[6],  (P)[7]),  X3);                       \
    X0 = fminf(fminf((P)[8],  (P)[9]),  X0);                       \
    X1 = fminf(fminf((P)[10], (P)[11]), X1);                       \
    X2 = fminf(fminf((P)[12], (P)[13]), X2);                       \
    X3 = fminf(fminf((P)[14], (P)[15]), X3);

// Deferred-fold step: issue 2 MFMAs on ring slot AQ, refill AQ (frag F+2),
// then fold the D-pair issued one STEP earlier (~70cy old -> fold never
// waits on MFMA latency), finally advance the D pipeline.
#define STEP(AQ, FN, DO_LOAD)                                               \
    {                                                                       \
        f32x16 dn0 = __builtin_amdgcn_mfma_f32_32x32x16_bf16(AQ, bq0, zc, 0, 0, 0); \
        f32x16 dn1 = __builtin_amdgcn_mfma_f32_32x32x16_bf16(AQ, bq1, zc, 0, 0, 0); \
        if (DO_LOAD) AQ = sp[(FN) * 32 + l31];                              \
        FOLD8(pp0, c0, c1, c2, c3);                                         \
        FOLD8(pp1, c4, c5, c6, c7);                                         \
        pp0 = dn0; pp1 = dn1;                                               \
    }

// Stage the 32KB chunk (2048 uint4) into sref via async DMA.
// Per wave: 4 x global_load_lds(16B): wave-uniform LDS base + lane*16.
#define STAGE()                                                             \
    _Pragma("unroll")                                                       \
    for (int i = 0; i < GLDS_PER_WAVE; ++i)                                 \
        __builtin_amdgcn_global_load_lds(                                   \
            (const unsigned*)(rgl + wid * 256 + i * 64 + lane),             \
            (unsigned*)&sref[wid * 256 + i * 64], 16, 0, 0);

// ---------------------------------------------------------------------------
// Kernel 2: per block = one (quarter, dir, b, 512-query group), 8 waves,
// 2 blocks/CU (grid 512, 32KB LDS) = 4 waves/SIMD.  Each wave owns 64 query
// cols (2 persistent B-frags); each A-frag ds_read feeds 2 MFMAs.  The ref
// walk runs REPEAT times (diagnostic; idempotent).  Epilogue: clamp >= 0,
// uint atomicMin into minpart (2 per lane 0-31).
// D layout (m74/m101): col = lane&31, row = (r&3)+8*(r>>2)+4*(lane>>5).
// ---------------------------------------------------------------------------
__global__ __launch_bounds__(THREADS, 4) void chamfer_kernel(
    const uint4* __restrict__ refpack, const uint4* __restrict__ qpack,
    unsigned* __restrict__ minpart) {
    __shared__ uint4 sref[CHUNK];          // 32 KB -> 2 blocks/CU (grid=512)

    int tid  = threadIdx.x;
    int blk  = blockIdx.x;                 // [0, 512)
    int quart= blk >> 7;                   // ref quarter 0..3
    int dir  = (blk >> 6) & 1;             // 0: q=preds r=gts; 1: q=gts r=preds
    int b    = (blk >> 4) & 3;
    int qg   = blk & 15;                   // query group of 512
    int rset = dir;
    int qset = dir ^ 1;
    int wid  = tid >> 6;                   // 0..7
    int lane = tid & 63;
    int l31  = lane & 31;

    const uint4* rgl = refpack + (size_t)(rset * BB + b) * NPTS
                     + (size_t)quart * QUARTN;

    // Persistent query B-frags: lane l31 = query col; lanes 32-63 zero
    // (K slots 8-15 of B are 0, so A's lane-32-63 half contributes 0 and
    // may hold garbage -- only lanes 0-31 of A matter).
    size_t qoff = (size_t)(qset * BB + b) * NPTS + (size_t)qg * QBLK
                + (size_t)wid * QPWV;
    bf16x8 bq0 = {0, 0, 0, 0, 0, 0, 0, 0};
    bf16x8 bq1 = {0, 0, 0, 0, 0, 0, 0, 0};
    if (lane < 32) {
        bq0 = ((const bf16x8*)qpack)[qoff + l31];
        bq1 = ((const bf16x8*)qpack)[qoff + 32 + l31];
    }

    f32x16 zc;
    #pragma unroll
    for (int r = 0; r < 16; ++r) zc[r] = 0.0f;

    float c0 = 3.0e38f, c1 = 3.0e38f, c2 = 3.0e38f, c3 = 3.0e38f;
    float c4 = 3.0e38f, c5 = 3.0e38f, c6 = 3.0e38f, c7 = 3.0e38f;

    // Prime the depth-1 D pipeline with +INF (first fold = no-op); pp
    // carries across rep boundaries (each rep's first STEP folds the last
    // D-pair of the previous rep -- valid, it is a real distance frag).
    f32x16 pp0, pp1;
    #pragma unroll
    for (int r = 0; r < 16; ++r) { pp0[r] = 3.0e38f; pp1[r] = 3.0e38f; }

    for (int rep = 0; rep < REPEAT; ++rep) {
        __syncthreads();                   // prior rep's LDS reads complete
        STAGE();
        __syncthreads();                   // DMA drained: chunk ready

        const bf16x8* sp = (const bf16x8*)sref;

        // Depth-2 prefetch ring (frags 0-1).
        bf16x8 a0 = sp[0 * 32 + l31];
        bf16x8 a1 = sp[1 * 32 + l31];

        // 32 macro-steps x 2 frags; ds offsets compile-time after unroll.
        #pragma unroll
        for (int m = 0; m < NFRAG / 2; ++m) {
            const bool L = (m < NFRAG / 2 - 1);      // last pair: no refill
            STEP(a0, (m + 1) * 2 + 0, L);
            STEP(a1, (m + 1) * 2 + 1, L);
        }
    }
    FOLD8(pp0, c0, c1, c2, c3);             // drain the D pipeline
    FOLD8(pp1, c4, c5, c6, c7);

    // Per-query partial min: lane halves hold complementary ref-rows.
    float m0 = fminf(fminf(c0, c1), fminf(c2, c3));
    m0 = fminf(m0, __shfl_xor(m0, 32, 64));
    float m1 = fminf(fminf(c4, c5), fminf(c6, c7));
    m1 = fminf(m1, __shfl_xor(m1, 32, 64));

    // Clamp >= 0 then uint atomicMin (order-isomorphic for nonneg floats).
    size_t qid = (size_t)(dir * BB + b) * NPTS + (size_t)qg * QBLK
               + (size_t)wid * QPWV;
    if (lane < 32) {
        atomicMin(minpart + qid + l31,      __float_as_uint(fmaxf(m0, 0.0f)));
        atomicMin(minpart + qid + 32 + l31, __float_as_uint(fmaxf(m1, 0.0f)));
    }
}

// ---------------------------------------------------------------------------
// Kernel 3: merge — sqrt + sum + atomicAdd.  64 blocks x 256 thr, 4 queries
// per thread (uint4).  Each block's 1024 queries lie within one (dir,b).
// ---------------------------------------------------------------------------
__global__ __launch_bounds__(256) void merge_kernel(
    const unsigned* __restrict__ minpart, float* __restrict__ out) {
    int t  = blockIdx.x * 256 + threadIdx.x;       // uint4 index
    uint4 v = ((const uint4*)minpart)[t];
    float d = sqrtf(__uint_as_float(v.x)) + sqrtf(__uint_as_float(v.y))
            + sqrtf(__uint_as_float(v.z)) + sqrtf(__uint_as_float(v.w));
    int b = (blockIdx.x >> 3) & 3;                 // (blk*1024 >> 13) & 3

    #pragma unroll
    for (int off = 32; off > 0; off >>= 1)
        d += __shfl_down(d, off, 64);

    __shared__ float wsum[4];
    int lane = threadIdx.x & 63;
    int wid  = threadIdx.x >> 6;
    if (lane == 0) wsum[wid] = d;
    __syncthreads();
    if (threadIdx.x == 0)
        atomicAdd(out + b, wsum[0] + wsum[1] + wsum[2] + wsum[3]);
}

extern "C" void kernel_launch(void* const* d_in, const int* in_sizes, int n_in,
                              void* d_out, int out_size, void* d_ws, size_t ws_size,
                              hipStream_t stream) {
    const float* gts   = (const float*)d_in[0];
    const float* preds = (const float*)d_in[1];
    float* out = (float*)d_out;

    char* ws = (char*)d_ws;
    uint4*    refpack = (uint4*)ws;                                // 1 MiB
    uint4*    qpack   = (uint4*)(ws + (size_t)NQ_TOTAL * 16);      // 1 MiB
    unsigned* minpart = (unsigned*)(ws + (size_t)NQ_TOTAL * 32);   // 256 KiB

    pack_kernel<<<NQ_TOTAL / 256, 256, 0, stream>>>(
        gts, preds, refpack, qpack, minpart, out);

    chamfer_kernel<<<FBLK, THREADS, 0, stream>>>(refpack, qpack, minpart);

    merge_kernel<<<NQ_TOTAL / 4 / 256, 256, 0, stream>>>(minpart, out);
}

// Round 8
// 71.472 us; speedup vs baseline: 1.8315x; 1.8315x over previous
//
#include <hip/hip_runtime.h>
#include <math.h>

// Problem constants: gts/preds [4, 8192, 3] fp32; out [4] fp32.
#define BB 4
#define NPTS 8192
#define THREADS 512                    // 8 waves/block
#define NQ_TOTAL (2 * BB * NPTS)       // 65536 (dir,b,point) slots
#define QBLK 512                       // queries per block (8 waves x 64)
#define QPWV 64                        // queries per wave (2 B-frags)
#define QUARTN 2048                    // refs per block (4-way ref split)
#define NFRAG (QUARTN / 32)            // 64 A-frags
#define FBLK 512                       // 4 quarters x 2 dir x 4 b x 16 qgroups

typedef __attribute__((ext_vector_type(4)))  short bf16x4;   // K=8 MFMA A/B frag
typedef __attribute__((ext_vector_type(16))) float f32x16;   // MFMA C/D frag

// ws layout (uint2 = 8B "half-slot" planes):
//   refpl[2][NQ_TOTAL]: lo = [x,y,z,rr_hi], hi = [rr_lo,1,1,0]       1 MiB
//   qpl  [2][NQ_TOTAL]: lo = [-2x,-2y,-2z,1], hi = [1,qq_hi,qq_lo,0] 1 MiB
//   minpart: NQ_TOTAL uint (fp32-as-uint partial d^2 mins)           256 KiB
// MFMA dot (K=8) = -2 q.r + rr + qq = |q-r|^2 on bf16-rounded points.
//
// R23 (counter-driven, from the R22 REPEAT=6 diagnostic: MfmaUtil 52%,
// VALUBusy 60% at 13.9us/pass):
//  - v_mfma_f32_32x32x8_bf16 (K=8): our encoding uses exactly 8 K-slots,
//    so the old 32x32x16 path wasted half of every MFMA (zeroed B-upper).
//    Same MFMA count, half the MACs -> MFMA floor 6.8 -> ~3.4us/CU.
//    A/B layout: row/col = lane&31, K-half = lane>>5 (same convention the
//    zero-upper-B trick relied on), so both lane halves now carry real
//    data via lo/hi 8B planes.  C/D layout is 32x32-shape-determined ->
//    epilogue unchanged; numerics bit-identical (same 7-term dot).
//  - immediate fold, no D-pipeline regs: R22's pp=dn copies did not
//    rename under the 128-VGPR cap (VALUBusy 60% vs 3.4us fold floor);
//    per-wave MFMA-latency stalls are covered by 4 waves/SIMD.
//  - A-frag ds_read_b64 (half LDS bytes); REPEAT diagnostic removed.

__device__ __forceinline__ unsigned short f2bf(float f) {   // RNE f32->bf16
    unsigned u = __float_as_uint(f);
    u += 0x7FFF + ((u >> 16) & 1);
    return (unsigned short)(u >> 16);
}
__device__ __forceinline__ float bf2f(unsigned short h) {
    return __uint_as_float(((unsigned)h) << 16);
}

// ---------------------------------------------------------------------------
// Kernel 1: round coords to bf16, build lo/hi planes for ref and query
// sides.  Also zero-inits out[0..3] and re-inits minpart to FLT_MAX (ws is
// poisoned by the harness every iteration).
// ---------------------------------------------------------------------------
__global__ __launch_bounds__(256) void pack_kernel(
    const float* __restrict__ gts, const float* __restrict__ preds,
    uint2* __restrict__ refpl, uint2* __restrict__ qpl,
    unsigned* __restrict__ minpart, float* __restrict__ out) {
    int idx = blockIdx.x * 256 + threadIdx.x;
    if (idx < BB) out[idx] = 0.0f;
    if (idx >= NQ_TOTAL) return;
    minpart[idx] = 0x7F7FFFFFu;            // FLT_MAX bits
    int set  = idx / (BB * NPTS);          // 0 = gts, 1 = preds
    int pidx = idx - set * (BB * NPTS);
    const float* src = set ? preds : gts;
    unsigned short hx = f2bf(src[pidx * 3 + 0]);
    unsigned short hy = f2bf(src[pidx * 3 + 1]);
    unsigned short hz = f2bf(src[pidx * 3 + 2]);
    float fx = bf2f(hx), fy = bf2f(hy), fz = bf2f(hz);
    float rr = fmaf(fx, fx, fmaf(fy, fy, fz * fz));
    unsigned short hrr = f2bf(rr);
    unsigned short hlo = f2bf(rr - bf2f(hrr));
    const unsigned short ONE = 0x3F80;      // 1.0 bf16

    uint2 rlo, rhi;                         // ref slots 0-3 / 4-7
    rlo.x = (unsigned)hx  | ((unsigned)hy  << 16);   // [x, y]
    rlo.y = (unsigned)hz  | ((unsigned)hrr << 16);   // [z, rrhi]
    rhi.x = (unsigned)hlo | ((unsigned)ONE << 16);   // [rrlo, 1]
    rhi.y = (unsigned)ONE;                           // [1, 0]
    refpl[idx]            = rlo;
    refpl[NQ_TOTAL + idx] = rhi;

    unsigned short nx = f2bf(-2.0f * fx);   // exact (coords already bf16)
    unsigned short ny = f2bf(-2.0f * fy);
    unsigned short nz = f2bf(-2.0f * fz);
    uint2 qlo, qhi;                         // query slots 0-3 / 4-7
    qlo.x = (unsigned)nx  | ((unsigned)ny  << 16);   // [-2x, -2y]
    qlo.y = (unsigned)nz  | ((unsigned)ONE << 16);   // [-2z, 1]
    qhi.x = (unsigned)ONE | ((unsigned)hrr << 16);   // [1, qqhi]
    qhi.y = (unsigned)hlo;                           // [qqlo, 0]
    qpl[idx]            = qlo;
    qpl[NQ_TOTAL + idx] = qhi;
}

// Fold one D frag into 4 independent running-min chains (v_min3 pairs).
#define FOLD8(P, X0, X1, X2, X3)                                   \
    X0 = fminf(fminf((P)[0],  (P)[1]),  X0);                       \
    X1 = fminf(fminf((P)[2],  (P)[3]),  X1);                       \
    X2 = fminf(fminf((P)[4],  (P)[5]),  X2);                       \
    X3 = fminf(fminf((P)[6],  (P)[7]),  X3);                       \
    X0 = fminf(fminf((P)[8],  (P)[9]),  X0);                       \
    X1 = fminf(fminf((P)[10], (P)[11]), X1);                       \
    X2 = fminf(fminf((P)[12], (P)[13]), X2);                       \
    X3 = fminf(fminf((P)[14], (P)[15]), X3);

#define MFMA8(A, B, C) __builtin_amdgcn_mfma_f32_32x32x8bf16_1k(A, B, C, 0, 0, 0)

// One step: 2 K=8 MFMAs consume ring slot AQ (frag F), refill AQ with frag
// F+4 if it exists, fold both D-frags immediately (per-wave result-latency
// stalls are covered by the 3 sibling waves on this SIMD).
#define STEP(AQ, FN, DO_LOAD)                                               \
    {                                                                       \
        f32x16 d0 = MFMA8(AQ, bq0, zc);                                     \
        f32x16 d1 = MFMA8(AQ, bq1, zc);                                     \
        if (DO_LOAD) AQ = spv[poff + (FN) * 32 + l31];                      \
        FOLD8(d0, c0, c1, c2, c3);                                          \
        FOLD8(d1, c4, c5, c6, c7);                                          \
    }

// Stage the 32KB ref chunk (lo plane 16KB + hi plane 16KB) via async DMA.
// Per wave: 2 x global_load_lds(16B) per plane; wave-uniform LDS base +
// lane*16 matches the per-lane linear global source.
#define STAGE()                                                             \
    _Pragma("unroll")                                                       \
    for (int i = 0; i < 2; ++i) {                                           \
        __builtin_amdgcn_global_load_lds(                                   \
            (const unsigned*)(rlo_src + i * 1024 + wid * 128 + lane * 2),   \
            (unsigned*)&sref[0][i * 1024 + wid * 128], 16, 0, 0);           \
        __builtin_amdgcn_global_load_lds(                                   \
            (const unsigned*)(rhi_src + i * 1024 + wid * 128 + lane * 2),   \
            (unsigned*)&sref[1][i * 1024 + wid * 128], 16, 0, 0);           \
    }

// ---------------------------------------------------------------------------
// Kernel 2: per block = one (quarter, dir, b, 512-query group), 8 waves,
// 2 blocks/CU (grid 512, 32KB LDS) = 4 waves/SIMD.  Each wave owns 64 query
// cols (2 persistent B-frags); each A-frag ds_read_b64 feeds 2 K=8 MFMAs.
// Epilogue: clamp >= 0, uint atomicMin into minpart (2 per lane 0-31).
// D layout (m74/m101): col = lane&31, row = (r&3)+8*(r>>2)+4*(lane>>5).
// ---------------------------------------------------------------------------
__global__ __launch_bounds__(THREADS, 4) void chamfer_kernel(
    const uint2* __restrict__ refpl, const uint2* __restrict__ qpl,
    unsigned* __restrict__ minpart) {
    __shared__ uint2 sref[2][QUARTN];      // 32 KB: [0]=lo plane, [1]=hi

    int tid  = threadIdx.x;
    int blk  = blockIdx.x;                 // [0, 512)
    int quart= blk >> 7;                   // ref quarter 0..3
    int dir  = (blk >> 6) & 1;             // 0: q=preds r=gts; 1: q=gts r=preds
    int b    = (blk >> 4) & 3;
    int qg   = blk & 15;                   // query group of 512
    int rset = dir;
    int qset = dir ^ 1;
    int wid  = tid >> 6;                   // 0..7
    int lane = tid & 63;
    int l31  = lane & 31;
    int khalf= lane >> 5;                  // 0 = K slots 0-3, 1 = K slots 4-7

    size_t rbase = (size_t)(rset * BB + b) * NPTS + (size_t)quart * QUARTN;
    const uint2* rlo_src = refpl + rbase;
    const uint2* rhi_src = refpl + NQ_TOTAL + rbase;

    // Stage the chunk (async; drained by the __syncthreads below).
    STAGE();

    // Persistent query B-frags: col = l31; this lane's K-half from the
    // matching plane.  ALL 64 lanes carry real data now (K=8 fully used).
    size_t qoff = (size_t)(qset * BB + b) * NPTS + (size_t)qg * QBLK
                + (size_t)wid * QPWV;
    const bf16x4* qv = (const bf16x4*)qpl;
    bf16x4 bq0 = qv[(size_t)khalf * NQ_TOTAL + qoff + l31];
    bf16x4 bq1 = qv[(size_t)khalf * NQ_TOTAL + qoff + 32 + l31];
    __syncthreads();                       // drains vmcnt: chunk ready

    f32x16 zc;
    #pragma unroll
    for (int r = 0; r < 16; ++r) zc[r] = 0.0f;

    float c0 = 3.0e38f, c1 = 3.0e38f, c2 = 3.0e38f, c3 = 3.0e38f;
    float c4 = 3.0e38f, c5 = 3.0e38f, c6 = 3.0e38f, c7 = 3.0e38f;

    const bf16x4* spv = (const bf16x4*)sref;
    const int poff = khalf * QUARTN;       // this lane's plane in LDS

    // Depth-4 prefetch ring (frags 0-3).
    bf16x4 a0 = spv[poff + 0 * 32 + l31];
    bf16x4 a1 = spv[poff + 1 * 32 + l31];
    bf16x4 a2 = spv[poff + 2 * 32 + l31];
    bf16x4 a3 = spv[poff + 3 * 32 + l31];

    // 16 macro-steps x 4 frags; ds offsets compile-time after unroll.
    #pragma unroll
    for (int m = 0; m < NFRAG / 4; ++m) {
        const bool L = (m < NFRAG / 4 - 1);          // last quartet: no refill
        STEP(a0, (m + 1) * 4 + 0, L);
        STEP(a1, (m + 1) * 4 + 1, L);
        STEP(a2, (m + 1) * 4 + 2, L);
        STEP(a3, (m + 1) * 4 + 3, L);
    }

    // Per-query partial min: lane halves hold complementary ref-rows.
    float m0 = fminf(fminf(c0, c1), fminf(c2, c3));
    m0 = fminf(m0, __shfl_xor(m0, 32, 64));
    float m1 = fminf(fminf(c4, c5), fminf(c6, c7));
    m1 = fminf(m1, __shfl_xor(m1, 32, 64));

    // Clamp >= 0 then uint atomicMin (order-isomorphic for nonneg floats).
    size_t qid = (size_t)(dir * BB + b) * NPTS + (size_t)qg * QBLK
               + (size_t)wid * QPWV;
    if (lane < 32) {
        atomicMin(minpart + qid + l31,      __float_as_uint(fmaxf(m0, 0.0f)));
        atomicMin(minpart + qid + 32 + l31, __float_as_uint(fmaxf(m1, 0.0f)));
    }
}

// ---------------------------------------------------------------------------
// Kernel 3: merge — sqrt + sum + atomicAdd.  64 blocks x 256 thr, 4 queries
// per thread (uint4).  Each block's 1024 queries lie within one (dir,b).
// ---------------------------------------------------------------------------
__global__ __launch_bounds__(256) void merge_kernel(
    const unsigned* __restrict__ minpart, float* __restrict__ out) {
    int t  = blockIdx.x * 256 + threadIdx.x;       // uint4 index
    uint4 v = ((const uint4*)minpart)[t];
    float d = sqrtf(__uint_as_float(v.x)) + sqrtf(__uint_as_float(v.y))
            + sqrtf(__uint_as_float(v.z)) + sqrtf(__uint_as_float(v.w));
    int b = (blockIdx.x >> 3) & 3;                 // (blk*1024 >> 13) & 3

    #pragma unroll
    for (int off = 32; off > 0; off >>= 1)
        d += __shfl_down(d, off, 64);

    __shared__ float wsum[4];
    int lane = threadIdx.x & 63;
    int wid  = threadIdx.x >> 6;
    if (lane == 0) wsum[wid] = d;
    __syncthreads();
    if (threadIdx.x == 0)
        atomicAdd(out + b, wsum[0] + wsum[1] + wsum[2] + wsum[3]);
}

extern "C" void kernel_launch(void* const* d_in, const int* in_sizes, int n_in,
                              void* d_out, int out_size, void* d_ws, size_t ws_size,
                              hipStream_t stream) {
    const float* gts   = (const float*)d_in[0];
    const float* preds = (const float*)d_in[1];
    float* out = (float*)d_out;

    char* ws = (char*)d_ws;
    uint2*    refpl   = (uint2*)ws;                                // 1 MiB
    uint2*    qpl     = (uint2*)(ws + (size_t)NQ_TOTAL * 16);      // 1 MiB
    unsigned* minpart = (unsigned*)(ws + (size_t)NQ_TOTAL * 32);   // 256 KiB

    pack_kernel<<<NQ_TOTAL / 256, 256, 0, stream>>>(
        gts, preds, refpl, qpl, minpart, out);

    chamfer_kernel<<<FBLK, THREADS, 0, stream>>>(refpl, qpl, minpart);

    merge_kernel<<<NQ_TOTAL / 4 / 256, 256, 0, stream>>>(minpart, out);
}

// Round 9
// 68.226 us; speedup vs baseline: 1.9187x; 1.0476x over previous
//
#include <hip/hip_runtime.h>
#include <math.h>

// Problem constants: gts/preds [4, 8192, 3] fp32; out [4] fp32.
#define BB 4
#define NPTS 8192
#define THREADS 512                    // 8 waves/block
#define NQ_TOTAL (2 * BB * NPTS)       // 65536 (dir,b,point) query slots
#define QBLK 512                       // queries per block (8 waves x 64)
#define QPWV 64                        // queries per wave (2 B-frags)
#define QUARTN 2048                    // refs per block (4-way ref split)
#define NFRAG (QUARTN / 32)            // 64 A-frags
#define FBLK 512                       // 4 quarters x 2 dir x 4 b x 16 qgroups

typedef __attribute__((ext_vector_type(4)))  short bf16x4;   // K=8 MFMA A/B frag
typedef __attribute__((ext_vector_type(16))) float f32x16;   // MFMA C/D frag

// ws layout:
//   minpart: float[4][NQ_TOTAL] per-quarter partial d^2 mins        1 MiB
// (refpack/qpack are GONE -- packing is fused into the main kernel.)
//
// R24 (launch-overhead fix of R23): R22's decomposition showed
// pack+merge+gaps ~= 6.5us and chamfer single-pass ~24us vs 13.9us/pass
// marginal -- ~10us of fixed cost: chamfer serialized behind pack's 2MiB
// writes, FLT_MAX init + 64K atomicMin RMW tail, launch ramp.  This
// version:
//  - fuses packing INTO chamfer: each block packs its own ref quarter
//    (24KB fp32, L2-hot, 16x redundant but ~0.3us VALU) into LDS planes;
//    each lane builds its 2 query B-frags from raw fp32 input.  Pack
//    kernel + gap + 2MiB round-trip deleted; chamfer starts immediately.
//  - plain-store min slices (minpart[quart][q]) instead of atomicMin:
//    no init pass, no RMW tail, no uint encoding.  Merge reads 4 slices.
//  - out[] zero-init moved to chamfer block 0 (stream-ordered vs merge).
// Main MFMA loop is identical to R23 (K=8 planes, 4 waves/SIMD, depth-4
// A-ring, immediate fold).  Numerics bit-identical: same f2bf rounding,
// same fp32 rr from rounded coords, same 7-term dot, same min/merge tree.

__device__ __forceinline__ unsigned short f2bf(float f) {   // RNE f32->bf16
    unsigned u = __float_as_uint(f);
    u += 0x7FFF + ((u >> 16) & 1);
    return (unsigned short)(u >> 16);
}
__device__ __forceinline__ float bf2f(unsigned short h) {
    return __uint_as_float(((unsigned)h) << 16);
}

#define ONE16 ((unsigned short)0x3F80)      // 1.0 bf16

// Pack one ref point (fp32 x,y,z) into lo/hi uint2 planes:
// lo = [x, y | z, rr_hi], hi = [rr_lo, 1 | 1, 0].
#define PACKR(X, Y, Z, LO, HI)                                              \
    {                                                                       \
        unsigned short hx = f2bf(X), hy = f2bf(Y), hz = f2bf(Z);            \
        float fx = bf2f(hx), fy = bf2f(hy), fz = bf2f(hz);                  \
        float rr = fmaf(fx, fx, fmaf(fy, fy, fz * fz));                     \
        unsigned short hrr = f2bf(rr), hlo = f2bf(rr - bf2f(hrr));          \
        (LO).x = (unsigned)hx  | ((unsigned)hy  << 16);                     \
        (LO).y = (unsigned)hz  | ((unsigned)hrr << 16);                     \
        (HI).x = (unsigned)hlo | ((unsigned)ONE16 << 16);                   \
        (HI).y = (unsigned)ONE16;                                           \
    }

// Build this lane's K-half of a query B-frag from fp32 x,y,z:
// khalf0 = [-2x,-2y,-2z,1], khalf1 = [1,qq_hi,qq_lo,0].
#define PACKQ(X, Y, Z, BQ)                                                  \
    {                                                                       \
        unsigned short hx = f2bf(X), hy = f2bf(Y), hz = f2bf(Z);            \
        float fx = bf2f(hx), fy = bf2f(hy), fz = bf2f(hz);                  \
        float qq = fmaf(fx, fx, fmaf(fy, fy, fz * fz));                     \
        unsigned short hq = f2bf(qq), hql = f2bf(qq - bf2f(hq));            \
        if (khalf == 0) {                                                   \
            (BQ)[0] = (short)f2bf(-2.0f * fx);                              \
            (BQ)[1] = (short)f2bf(-2.0f * fy);                              \
            (BQ)[2] = (short)f2bf(-2.0f * fz);                              \
            (BQ)[3] = (short)ONE16;                                         \
        } else {                                                            \
            (BQ)[0] = (short)ONE16;                                         \
            (BQ)[1] = (short)hq;                                            \
            (BQ)[2] = (short)hql;                                           \
            (BQ)[3] = 0;                                                    \
        }                                                                   \
    }

// Fold one D frag into 4 independent running-min chains (v_min3 pairs).
#define FOLD8(P, X0, X1, X2, X3)                                   \
    X0 = fminf(fminf((P)[0],  (P)[1]),  X0);                       \
    X1 = fminf(fminf((P)[2],  (P)[3]),  X1);                       \
    X2 = fminf(fminf((P)[4],  (P)[5]),  X2);                       \
    X3 = fminf(fminf((P)[6],  (P)[7]),  X3);                       \
    X0 = fminf(fminf((P)[8],  (P)[9]),  X0);                       \
    X1 = fminf(fminf((P)[10], (P)[11]), X1);                       \
    X2 = fminf(fminf((P)[12], (P)[13]), X2);                       \
    X3 = fminf(fminf((P)[14], (P)[15]), X3);

#define MFMA8(A, B, C) __builtin_amdgcn_mfma_f32_32x32x8bf16_1k(A, B, C, 0, 0, 0)

// One step: 2 K=8 MFMAs consume ring slot AQ (frag F), refill AQ with frag
// F+4 if it exists, fold both D-frags immediately (per-wave result-latency
// stalls are covered by the 3 sibling waves on this SIMD).
#define STEP(AQ, FN, DO_LOAD)                                               \
    {                                                                       \
        f32x16 d0 = MFMA8(AQ, bq0, zc);                                     \
        f32x16 d1 = MFMA8(AQ, bq1, zc);                                     \
        if (DO_LOAD) AQ = spv[poff + (FN) * 32 + l31];                      \
        FOLD8(d0, c0, c1, c2, c3);                                          \
        FOLD8(d1, c4, c5, c6, c7);                                          \
    }

// ---------------------------------------------------------------------------
// Kernel 1 (fused pack + chamfer): per block = one (quarter, dir, b,
// 512-query group), 8 waves, 2 blocks/CU (grid 512, 32KB LDS) = 4 waves/
// SIMD.  Block packs its 2048-ref quarter from raw fp32 into LDS bf16
// planes; each lane builds 2 query B-frags from raw fp32.  Main loop: each
// A-frag ds_read_b64 feeds 2 K=8 MFMAs.  Epilogue: clamp >= 0, plain-store
// partial mins into this quarter's minpart slice.
// D layout (m74/m101): col = lane&31, row = (r&3)+8*(r>>2)+4*(lane>>5).
// ---------------------------------------------------------------------------
__global__ __launch_bounds__(THREADS, 4) void chamfer_kernel(
    const float* __restrict__ gts, const float* __restrict__ preds,
    float* __restrict__ minpart, float* __restrict__ out) {
    __shared__ uint2 sref[2][QUARTN];      // 32 KB: [0]=lo plane, [1]=hi

    int tid  = threadIdx.x;
    int blk  = blockIdx.x;                 // [0, 512)
    int quart= blk >> 7;                   // ref quarter 0..3
    int dir  = (blk >> 6) & 1;             // 0: q=preds r=gts; 1: q=gts r=preds
    int b    = (blk >> 4) & 3;
    int qg   = blk & 15;                   // query group of 512
    int wid  = tid >> 6;                   // 0..7
    int lane = tid & 63;
    int l31  = lane & 31;
    int khalf= lane >> 5;                  // 0 = K slots 0-3, 1 = K slots 4-7

    if (blk == 0 && tid < BB) out[tid] = 0.0f;   // stream-ordered vs merge

    // ---- Query B-frags from raw fp32 (L2-hot, 384B window per wave-half).
    const float* qsrc = (dir ^ 1) ? preds : gts;
    size_t qpt = (size_t)b * NPTS + (size_t)qg * QBLK + (size_t)wid * QPWV + l31;
    float qx0 = qsrc[qpt * 3],        qy0 = qsrc[qpt * 3 + 1],
          qz0 = qsrc[qpt * 3 + 2];
    float qx1 = qsrc[(qpt + 32) * 3], qy1 = qsrc[(qpt + 32) * 3 + 1],
          qz1 = qsrc[(qpt + 32) * 3 + 2];
    bf16x4 bq0, bq1;
    PACKQ(qx0, qy0, qz0, bq0);
    PACKQ(qx1, qy1, qz1, bq1);

    // ---- Pack this block's 2048-ref quarter into LDS planes.
    // Thread t packs points 4t..4t+3 (3 coalesced-ish float4 loads, L2-hot).
    const float* rsrc = dir ? preds : gts;
    size_t rfbase = ((size_t)b * NPTS + (size_t)quart * QUARTN) * 3;
    const float4* rf4 = (const float4*)(rsrc + rfbase);
    float4 f0 = rf4[3 * tid], f1 = rf4[3 * tid + 1], f2 = rf4[3 * tid + 2];
    uint2 l0, l1, l2, l3, h0, h1, h2, h3;
    PACKR(f0.x, f0.y, f0.z, l0, h0);
    PACKR(f0.w, f1.x, f1.y, l1, h1);
    PACKR(f1.z, f1.w, f2.x, l2, h2);
    PACKR(f2.y, f2.z, f2.w, l3, h3);
    uint4* dlo = (uint4*)&sref[0][4 * tid];
    dlo[0] = make_uint4(l0.x, l0.y, l1.x, l1.y);
    dlo[1] = make_uint4(l2.x, l2.y, l3.x, l3.y);
    uint4* dhi = (uint4*)&sref[1][4 * tid];
    dhi[0] = make_uint4(h0.x, h0.y, h1.x, h1.y);
    dhi[1] = make_uint4(h2.x, h2.y, h3.x, h3.y);
    __syncthreads();                       // planes ready

    f32x16 zc;
    #pragma unroll
    for (int r = 0; r < 16; ++r) zc[r] = 0.0f;

    float c0 = 3.0e38f, c1 = 3.0e38f, c2 = 3.0e38f, c3 = 3.0e38f;
    float c4 = 3.0e38f, c5 = 3.0e38f, c6 = 3.0e38f, c7 = 3.0e38f;

    const bf16x4* spv = (const bf16x4*)sref;
    const int poff = khalf * QUARTN;       // this lane's plane in LDS

    // Depth-4 prefetch ring (frags 0-3).
    bf16x4 a0 = spv[poff + 0 * 32 + l31];
    bf16x4 a1 = spv[poff + 1 * 32 + l31];
    bf16x4 a2 = spv[poff + 2 * 32 + l31];
    bf16x4 a3 = spv[poff + 3 * 32 + l31];

    // 16 macro-steps x 4 frags; ds offsets compile-time after unroll.
    #pragma unroll
    for (int m = 0; m < NFRAG / 4; ++m) {
        const bool L = (m < NFRAG / 4 - 1);          // last quartet: no refill
        STEP(a0, (m + 1) * 4 + 0, L);
        STEP(a1, (m + 1) * 4 + 1, L);
        STEP(a2, (m + 1) * 4 + 2, L);
        STEP(a3, (m + 1) * 4 + 3, L);
    }

    // Per-query partial min: lane halves hold complementary ref-rows.
    float m0 = fminf(fminf(c0, c1), fminf(c2, c3));
    m0 = fminf(m0, __shfl_xor(m0, 32, 64));
    float m1 = fminf(fminf(c4, c5), fminf(c6, c7));
    m1 = fminf(m1, __shfl_xor(m1, 32, 64));

    // Plain-store this quarter's partial mins (clamped >= 0): no atomics.
    size_t qid = (size_t)(dir * BB + b) * NPTS + (size_t)qg * QBLK
               + (size_t)wid * QPWV;
    float* mp = minpart + (size_t)quart * NQ_TOTAL + qid;
    if (lane < 32) {
        mp[l31]      = fmaxf(m0, 0.0f);
        mp[32 + l31] = fmaxf(m1, 0.0f);
    }
}

// ---------------------------------------------------------------------------
// Kernel 2: merge — min across the 4 quarter slices, sqrt, sum, atomicAdd.
// 64 blocks x 256 thr, 4 queries per thread (float4 per slice).
// ---------------------------------------------------------------------------
__global__ __launch_bounds__(256) void merge_kernel(
    const float* __restrict__ minpart, float* __restrict__ out) {
    int t = blockIdx.x * 256 + threadIdx.x;        // float4 index [0,16384)
    const float4* mp4 = (const float4*)minpart;
    float4 v0 = mp4[t];
    float4 v1 = mp4[t + NQ_TOTAL / 4];
    float4 v2 = mp4[t + 2 * (NQ_TOTAL / 4)];
    float4 v3 = mp4[t + 3 * (NQ_TOTAL / 4)];
    float mx = fminf(fminf(v0.x, v1.x), fminf(v2.x, v3.x));
    float my = fminf(fminf(v0.y, v1.y), fminf(v2.y, v3.y));
    float mz = fminf(fminf(v0.z, v1.z), fminf(v2.z, v3.z));
    float mw = fminf(fminf(v0.w, v1.w), fminf(v2.w, v3.w));
    float d = sqrtf(mx) + sqrtf(my) + sqrtf(mz) + sqrtf(mw);
    int b = (t >> 11) & 3;                         // uniform within a block

    #pragma unroll
    for (int off = 32; off > 0; off >>= 1)
        d += __shfl_down(d, off, 64);

    __shared__ float wsum[4];
    int lane = threadIdx.x & 63;
    int wid  = threadIdx.x >> 6;
    if (lane == 0) wsum[wid] = d;
    __syncthreads();
    if (threadIdx.x == 0)
        atomicAdd(out + b, wsum[0] + wsum[1] + wsum[2] + wsum[3]);
}

extern "C" void kernel_launch(void* const* d_in, const int* in_sizes, int n_in,
                              void* d_out, int out_size, void* d_ws, size_t ws_size,
                              hipStream_t stream) {
    const float* gts   = (const float*)d_in[0];
    const float* preds = (const float*)d_in[1];
    float* out = (float*)d_out;

    float* minpart = (float*)d_ws;                 // 4 x 256 KiB slices

    chamfer_kernel<<<FBLK, THREADS, 0, stream>>>(gts, preds, minpart, out);

    merge_kernel<<<NQ_TOTAL / 4 / 256, 256, 0, stream>>>(minpart, out);
}